// Round 20
// baseline (128.204 us; speedup 1.0000x reference)
//
#include <hip/hip_runtime.h>
#include <hip/hip_bf16.h>

typedef __bf16 bf16x8 __attribute__((ext_vector_type(8)));
typedef float  f32x4  __attribute__((ext_vector_type(4)));
typedef unsigned short ushort_t;

#define NN 468

// wext element offsets (ushort), fragment-major planes (NOT swizzled)
#define W1H 0
#define W1L 8192
#define W2H 16384
#define W2L 49152
#define W3H 81920
#define W3L 114688

// ---- per-unit LDS offsets (relative to unit base); unit span 77,768 B ----
// X overlaid @0 (X0 32096 / X1 27200 / X2 43296)
// Y1 @32096 (2x14336) | Y2 @27200 (2x24576 full-K) | Y3 @43296 (2x16384)
// lmst @76352 (1416). Pairwise-live sets disjoint (R16-verified).
#define UO_Y1 32096
#define UO_Y2 27200
#define UO_Y3 43296
#define UO_LM 76352
#define U_STRIDE 77768
#define L_DTAB  (2*U_STRIDE)        // 155536, 472 B (shared: same r0)
#define L_POOLA (L_DTAB + 472)      // 156008, 512 B
#define L_POOLB (L_POOLA + 512)     // 156520, 512 B -> total 157032

#define MFMA3(d, ah, al, wh, wl)                                        \
    d = __builtin_amdgcn_mfma_f32_16x16x32_bf16(ah, wh, d, 0, 0, 0);    \
    d = __builtin_amdgcn_mfma_f32_16x16x32_bf16(ah, wl, d, 0, 0, 0);    \
    d = __builtin_amdgcn_mfma_f32_16x16x32_bf16(al, wh, d, 0, 0, 0);

// ---------------------------------------------------------------------------
__device__ __forceinline__ void pack_split4(const float* y,
                                            ushort_t* hdst, ushort_t* ldst) {
    ushort_t h[4], l[4];
    #pragma unroll
    for (int j = 0; j < 4; ++j) {
        __hip_bfloat16 hb = __float2bfloat16(y[j]);
        float hf = __bfloat162float(hb);
        __hip_bfloat16 lb = __float2bfloat16(y[j] - hf);
        h[j] = *(ushort_t*)&hb; l[j] = *(ushort_t*)&lb;
    }
    uint2 hv = make_uint2((unsigned)h[0] | ((unsigned)h[1] << 16),
                          (unsigned)h[2] | ((unsigned)h[3] << 16));
    uint2 lv = make_uint2((unsigned)l[0] | ((unsigned)l[1] << 16),
                          (unsigned)l[2] | ((unsigned)l[3] << 16));
    *(uint2*)hdst = hv;
    *(uint2*)ldst = lv;
}

__device__ __forceinline__ int frag_off(int r, int k, int K16) {
    return (r >> 4) * K16 + (k >> 5) * 512 + ((k >> 3) & 3) * 128
         + (r & 15) * 8 + (k & 7);
}

// swizzled Y-plane offset (LDS): unit' = q*16 + ((r ^ 2q) & 15)
__device__ __forceinline__ int ywoff(int r, int k4, int K16) {
    int q = (k4 >> 3) & 3;
    int u = q * 16 + (((r & 15) ^ (q << 1)) & 15);
    return (r >> 4) * K16 + (k4 >> 5) * 512 + u * 8 + (k4 & 7);
}

// ---------------------------------------------------------------------------
// Per-unit phase bodies — R16's verified 512-thread code, ltid-parameterized.
// Frames: X0 l0: gr=r0-27+l0 (0..117) | Y1/X1 lr1: gr=r0-18+lr1 (0..99/112)
//         Y2/X2 lr2: gr=r0-9+lr2 (0..81/96) | Y3 lr3: gr=r0+lr3 (0..63)
// ---------------------------------------------------------------------------
__device__ __forceinline__ void ph_stage(const float* Lm, float* lmst,
                                         float* pool, float* dtab, bool do_dtab,
                                         int b, int r0, int ltid) {
    if (do_dtab && ltid < 118) {
        int ri = r0 - 27 + ltid;
        float dv = 0.f;
        if (ri >= 0 && ri < NN) {
            int lo = ri - 9; if (lo < 0) lo = 0;
            int hi = ri + 9; if (hi > NN - 1) hi = NN - 1;
            dv = 1.0f / sqrtf((float)(hi - lo + 1));
        }
        dtab[ltid] = dv;
    }
    if (ltid < 354) {
        int g = (r0 - 27) * 3 + ltid;
        lmst[ltid] = (g >= 0 && g < NN * 3) ? Lm[(size_t)b * (NN * 3) + g] : 0.f;
    }
    if (ltid < 128) pool[ltid] = 0.f;
}

__device__ __forceinline__ void ph_enc(float* X, const float* lmst,
                                       const float* dtab, const float* We,
                                       const float* be, int ltid) {
    const int c = ltid & 63;
    const float w0 = We[c], w1 = We[64 + c], w2 = We[128 + c], bk = be[c];
    for (int l0 = ltid >> 6; l0 < 118; l0 += 8) {
        float x = bk + lmst[l0*3]*w0 + lmst[l0*3+1]*w1 + lmst[l0*3+2]*w2;
        X[l0 * 68 + c] = x * dtab[l0];
    }
}

__device__ __forceinline__ void ph_band1(const float* X, ushort_t* Y1h,
                                         ushort_t* Y1l, const float* dtab,
                                         int ltid) {
    const int c4 = (ltid & 15) << 2;
    const int base = (ltid >> 4) * 4;
    if (base < 100) {
        f32x4 ws = {};
        #pragma unroll
        for (int d = 0; d < 19; ++d)
            ws += *(const f32x4*)(X + (base + d) * 68 + c4);
        #pragma unroll
        for (int rr = 0; rr < 4; ++rr) {
            int row = base + rr;
            if (rr) ws += *(const f32x4*)(X + (row + 18) * 68 + c4)
                        - *(const f32x4*)(X + (row - 1)  * 68 + c4);
            float dv = dtab[row + 9];
            float y4[4] = {ws[0]*dv, ws[1]*dv, ws[2]*dv, ws[3]*dv};
            int off = ywoff(row, c4, 1024);
            pack_split4(y4, Y1h + off, Y1l + off);
        }
    } else if (base < 112) {
        float z4[4] = {0.f, 0.f, 0.f, 0.f};
        #pragma unroll
        for (int rr = 0; rr < 4; ++rr) {
            int row = base + rr;
            if (row < 112) {
                int off = ywoff(row, c4, 1024);
                pack_split4(z4, Y1h + off, Y1l + off);
            }
        }
    }
}

__device__ __forceinline__ void ph_gemm1(const ushort_t* Y1h, const ushort_t* Y1l,
                                         const ushort_t* wext, f32x4 (&acc1)[4][2],
                                         int ltid) {
    const int lane = ltid & 63, wave = ltid >> 6;
    const int wm = wave & 1, wn = wave >> 1;
    const int lswz = (lane & 48) + (((lane & 15) ^ ((lane >> 4) << 1)) & 15);
    __builtin_amdgcn_s_setprio(1);
    #pragma unroll
    for (int kt = 0; kt < 2; ++kt) {
        bf16x8 a[4][2];
        #pragma unroll
        for (int mt = 0; mt < 4; ++mt) {
            int t = wm*4 + mt; if (t > 6) t = 6;
            int off = t * 1024 + kt * 512 + lswz * 8;
            a[mt][0] = *(const bf16x8*)(Y1h + off);
            a[mt][1] = *(const bf16x8*)(Y1l + off);
        }
        #pragma unroll
        for (int nt = 0; nt < 2; ++nt) {
            int woff = (nt*4 + wn) * 1024 + kt * 512 + lane * 8;
            bf16x8 wh = *(const bf16x8*)(wext + W1H + woff);
            bf16x8 wl = *(const bf16x8*)(wext + W1L + woff);
            #pragma unroll
            for (int mt = 0; mt < 4; ++mt) {
                MFMA3(acc1[mt][nt], a[mt][0], a[mt][1], wh, wl);
            }
        }
    }
    __builtin_amdgcn_s_setprio(0);
}

__device__ __forceinline__ void ph_epi1(float* X, const f32x4 (&acc1)[4][2],
                                        const float* dtab, const float* b1,
                                        int kc, int ltid) {
    const int lane = ltid & 63, wave = ltid >> 6;
    const int wm = wave & 1, wn = wave >> 1;
    const int l15 = lane & 15, lg = lane >> 4;
    #pragma unroll
    for (int mt = 0; mt < 4; ++mt) {
        int t = wm*4 + mt; if (t > 6) t = 6;
        int gcol = (kc*4 + wn)*16 + l15;
        int cl   = wn*16 + l15;
        float bv = b1[gcol];
        #pragma unroll
        for (int r = 0; r < 4; ++r) {
            int lr1 = t*16 + lg*4 + r;
            if (lr1 < 100)
                X[lr1*68 + cl] = dtab[lr1 + 9] * fmaxf(acc1[mt][kc][r] + bv, 0.f);
        }
    }
}

__device__ __forceinline__ void ph_band2(const float* X, ushort_t* Y2h,
                                         ushort_t* Y2l, const float* dtab,
                                         int kc, int ltid) {
    const int c4   = (ltid & 15) << 2;
    const int base = (ltid >> 4) * 3;
    f32x4 ws = {};
    if (base < 82) {
        #pragma unroll
        for (int d = 0; d < 19; ++d)
            ws += *(const f32x4*)(X + (base + d) * 68 + c4);
    }
    #pragma unroll
    for (int rr = 0; rr < 3; ++rr) {
        int row = base + rr;
        if (row < 96) {
            float y4[4] = {0.f, 0.f, 0.f, 0.f};
            if (row < 82) {
                if (rr) ws += *(const f32x4*)(X + (row + 18) * 68 + c4)
                            - *(const f32x4*)(X + (row - 1)  * 68 + c4);
                float dv = dtab[row + 18];
                y4[0] = ws[0]*dv; y4[1] = ws[1]*dv;
                y4[2] = ws[2]*dv; y4[3] = ws[3]*dv;
            }
            int off = ywoff(row, kc*64 + c4, 2048);
            pack_split4(y4, Y2h + off, Y2l + off);
        }
    }
}

__device__ __forceinline__ void ph_gemm2(const ushort_t* Y2h, const ushort_t* Y2l,
                                         const ushort_t* wext, f32x4 (&acc2)[3][4],
                                         int ltid) {
    const int lane = ltid & 63, wave = ltid >> 6;
    const int wm = wave & 1, wn = wave >> 1;
    const int lswz = (lane & 48) + (((lane & 15) ^ ((lane >> 4) << 1)) & 15);
    __builtin_amdgcn_s_setprio(1);
    #pragma unroll
    for (int kt = 0; kt < 4; ++kt) {
        bf16x8 a[3][2];
        #pragma unroll
        for (int mt = 0; mt < 3; ++mt) {
            int off = (wm*3 + mt) * 2048 + kt * 512 + lswz * 8;
            a[mt][0] = *(const bf16x8*)(Y2h + off);
            a[mt][1] = *(const bf16x8*)(Y2l + off);
        }
        #pragma unroll
        for (int nt = 0; nt < 4; ++nt) {
            int woff = (nt*4 + wn) * 2048 + kt * 512 + lane * 8;
            bf16x8 wh = *(const bf16x8*)(wext + W2H + woff);
            bf16x8 wl = *(const bf16x8*)(wext + W2L + woff);
            #pragma unroll
            for (int mt = 0; mt < 3; ++mt) {
                MFMA3(acc2[mt][nt], a[mt][0], a[mt][1], wh, wl);
            }
        }
    }
    __builtin_amdgcn_s_setprio(0);
}

__device__ __forceinline__ void ph_epi2(float* X, const f32x4 (&acc2)[3][4],
                                        const float* dtab, const float* b2,
                                        int nc, int ltid) {
    const int lane = ltid & 63, wave = ltid >> 6;
    const int wm = wave & 1, wn = wave >> 1;
    const int l15 = lane & 15, lg = lane >> 4;
    #pragma unroll
    for (int mt = 0; mt < 3; ++mt)
    #pragma unroll
    for (int q = 0; q < 2; ++q) {
        int gcol = ((nc*2 + q)*4 + wn)*16 + l15;
        int cl   = (q*4 + wn)*16 + l15;
        float bv = b2[gcol];
        #pragma unroll
        for (int r = 0; r < 4; ++r) {
            int lr2 = (wm*3 + mt)*16 + lg*4 + r;
            if (lr2 < 82)
                X[lr2*132 + cl] = dtab[lr2 + 18] * fmaxf(acc2[mt][nc*2 + q][r] + bv, 0.f);
        }
    }
}

__device__ __forceinline__ void ph_band3(const float* X, ushort_t* Y3h,
                                         ushort_t* Y3l, const float* dtab,
                                         int ltid) {
    const int c4   = (ltid & 31) << 2;
    const int base = (ltid >> 5) * 4;
    f32x4 ws = {};
    #pragma unroll
    for (int d = 0; d < 19; ++d)
        ws += *(const f32x4*)(X + (base + d) * 132 + c4);
    #pragma unroll
    for (int rr = 0; rr < 4; ++rr) {
        int row = base + rr;
        if (rr) ws += *(const f32x4*)(X + (row + 18) * 132 + c4)
                    - *(const f32x4*)(X + (row - 1)  * 132 + c4);
        float dv = dtab[row + 27];
        float y4[4] = {ws[0]*dv, ws[1]*dv, ws[2]*dv, ws[3]*dv};
        int off = ywoff(row, c4, 2048);
        pack_split4(y4, Y3h + off, Y3l + off);
    }
}

__device__ __forceinline__ void ph_gemm3(const ushort_t* Y3h, const ushort_t* Y3l,
                                         const ushort_t* wext, f32x4 (&acc3)[2][2],
                                         int nc, int ltid) {
    const int lane = ltid & 63, wave = ltid >> 6;
    const int wm = wave & 1, wn = wave >> 1;
    const int lswz = (lane & 48) + (((lane & 15) ^ ((lane >> 4) << 1)) & 15);
    __builtin_amdgcn_s_setprio(1);
    #pragma unroll
    for (int kt = 0; kt < 4; ++kt) {
        bf16x8 a0[2], a1[2];
        #pragma unroll
        for (int mt = 0; mt < 2; ++mt) {
            int aoff = (wm*2 + mt) * 2048 + kt * 512 + lswz * 8;
            a0[mt] = *(const bf16x8*)(Y3h + aoff);
            a1[mt] = *(const bf16x8*)(Y3l + aoff);
        }
        #pragma unroll
        for (int nt = 0; nt < 2; ++nt) {
            int woff = (nt*4 + wn) * 4096 + (nc*4 + kt) * 512 + lane * 8;
            bf16x8 wh = *(const bf16x8*)(wext + W3H + woff);
            bf16x8 wl = *(const bf16x8*)(wext + W3L + woff);
            #pragma unroll
            for (int mt = 0; mt < 2; ++mt) {
                MFMA3(acc3[mt][nt], a0[mt], a1[mt], wh, wl);
            }
        }
    }
    __builtin_amdgcn_s_setprio(0);
}

__device__ __forceinline__ void ph_pool_acc(const f32x4 (&acc3)[2][2], float* pool,
                                            const float* b3, int r0, int ltid) {
    const int lane = ltid & 63, wave = ltid >> 6;
    const int wm = wave & 1, wn = wave >> 1;
    const int l15 = lane & 15, lg = lane >> 4;
    #pragma unroll
    for (int nt = 0; nt < 2; ++nt) {
        int g_t = nt*4 + wn;
        float bv = b3[g_t*16 + l15];
        float cs = 0.f;
        #pragma unroll
        for (int mt = 0; mt < 2; ++mt)
        #pragma unroll
        for (int r = 0; r < 4; ++r) {
            int gr = r0 + (wm*2 + mt)*16 + lg*4 + r;
            if (gr < NN) cs += fmaxf(acc3[mt][nt][r] + bv, 0.f);
        }
        cs += __shfl_xor(cs, 16);
        cs += __shfl_xor(cs, 32);
        if (lane < 16) atomicAdd(&pool[g_t*16 + lane], cs);
    }
}

__device__ __forceinline__ void ph_pool_write(const float* pool, float* partial,
                                              int b, int rt, int ltid) {
    if (ltid < 128) partial[((size_t)b * 8 + rt) * 128 + ltid] = pool[ltid];
}

// ---------------------------------------------------------------------------
// fused2: two units per 1024-thread block; waves 0-7 = unit A, 8-15 = unit B.
// B's 13-phase R16 schedule shifted by ONE slot -> A MFMA slots {3,7,10,12}
// vs B {4,8,11,13}: zero collisions, every MFMA slot pairs with VALU work.
// Unlike R17 (one wave ran both phases serially), each wave runs only its
// unit's phase per slot -> true wave-level MFMA∥VALU overlap (m114).
// LDS 157,032 B -> 1 block/CU. launch_bounds(1024,4): 128-reg cap (R16: 64).
// ---------------------------------------------------------------------------
__global__ __launch_bounds__(1024, 4) void fused2(
    const float* __restrict__ Lm, const ushort_t* __restrict__ wext,
    const float* __restrict__ We, const float* __restrict__ be,
    const float* __restrict__ b1, const float* __restrict__ b2,
    const float* __restrict__ b3, float* __restrict__ partial)
{
    __shared__ __align__(16) char lds[157056];
    const int tid  = threadIdx.x;
    const int u    = tid >> 9;          // 0: waves 0-7, 1: waves 8-15
    const int ltid = tid & 511;
    char* ub = lds + u * U_STRIDE;
    float*    Xu   = (float*)ub;
    ushort_t* Y1h  = (ushort_t*)(ub + UO_Y1);  ushort_t* Y1l = Y1h + 7168;
    ushort_t* Y2h  = (ushort_t*)(ub + UO_Y2);  ushort_t* Y2l = Y2h + 12288;
    ushort_t* Y3h  = (ushort_t*)(ub + UO_Y3);  ushort_t* Y3l = Y3h + 8192;
    float*    lmst = (float*)(ub + UO_LM);
    float*    dtab = (float*)(lds + L_DTAB);
    float*    pool = (float*)(lds + (u ? L_POOLB : L_POOLA));

    const int rt = blockIdx.x;
    const int b  = blockIdx.y * 2 + u;
    const int r0 = rt * 64;

    f32x4 acc1[4][2] = {};
    f32x4 acc2[3][4] = {};
    f32x4 acc3[2][2] = {};

    #define BAR __syncthreads()
    // s0
    if (!u) ph_stage(Lm, lmst, pool, dtab, true, b, r0, ltid);
    BAR;
    // s1
    if (!u) ph_enc(Xu, lmst, dtab, We, be, ltid);
    else    ph_stage(Lm, lmst, pool, dtab, false, b, r0, ltid);
    BAR;
    // s2
    if (!u) ph_band1(Xu, Y1h, Y1l, dtab, ltid);
    else    ph_enc(Xu, lmst, dtab, We, be, ltid);
    BAR;
    // s3  (A: MFMA)
    if (!u) { ph_gemm1(Y1h, Y1l, wext, acc1, ltid);
              ph_epi1(Xu, acc1, dtab, b1, 0, ltid); }
    else    ph_band1(Xu, Y1h, Y1l, dtab, ltid);
    BAR;
    // s4  (B: MFMA)
    if (!u) ph_band2(Xu, Y2h, Y2l, dtab, 0, ltid);
    else  { ph_gemm1(Y1h, Y1l, wext, acc1, ltid);
            ph_epi1(Xu, acc1, dtab, b1, 0, ltid); }
    BAR;
    // s5
    if (!u) ph_epi1(Xu, acc1, dtab, b1, 1, ltid);
    else    ph_band2(Xu, Y2h, Y2l, dtab, 0, ltid);
    BAR;
    // s6
    if (!u) ph_band2(Xu, Y2h, Y2l, dtab, 1, ltid);
    else    ph_epi1(Xu, acc1, dtab, b1, 1, ltid);
    BAR;
    // s7  (A: MFMA)
    if (!u) ph_gemm2(Y2h, Y2l, wext, acc2, ltid);
    else    ph_band2(Xu, Y2h, Y2l, dtab, 1, ltid);
    BAR;
    // s8  (B: MFMA)
    if (!u) ph_epi2(Xu, acc2, dtab, b2, 0, ltid);
    else    ph_gemm2(Y2h, Y2l, wext, acc2, ltid);
    BAR;
    // s9
    if (!u) ph_band3(Xu, Y3h, Y3l, dtab, ltid);
    else    ph_epi2(Xu, acc2, dtab, b2, 0, ltid);
    BAR;
    // s10 (A: MFMA)
    if (!u) { ph_gemm3(Y3h, Y3l, wext, acc3, 0, ltid);
              ph_epi2(Xu, acc2, dtab, b2, 1, ltid); }
    else    ph_band3(Xu, Y3h, Y3l, dtab, ltid);
    BAR;
    // s11 (B: MFMA)
    if (!u) ph_band3(Xu, Y3h, Y3l, dtab, ltid);
    else  { ph_gemm3(Y3h, Y3l, wext, acc3, 0, ltid);
            ph_epi2(Xu, acc2, dtab, b2, 1, ltid); }
    BAR;
    // s12 (A: MFMA)
    if (!u) { ph_gemm3(Y3h, Y3l, wext, acc3, 1, ltid);
              ph_pool_acc(acc3, pool, b3, r0, ltid); }
    else    ph_band3(Xu, Y3h, Y3l, dtab, ltid);
    BAR;
    // s13 (B: MFMA)
    if (!u) ph_pool_write(pool, partial, b, rt, ltid);
    else  { ph_gemm3(Y3h, Y3l, wext, acc3, 1, ltid);
            ph_pool_acc(acc3, pool, b3, r0, ltid); }
    BAR;
    // s14
    if (u) ph_pool_write(pool, partial, b, rt, ltid);
    #undef BAR
}

// ---------------------------------------------------------------------------
__global__ __launch_bounds__(256) void wconv(
    const float* __restrict__ W1, const float* __restrict__ W2,
    const float* __restrict__ W3, ushort_t* __restrict__ wext)
{
    int i = blockIdx.x * 256 + threadIdx.x;
    float w; int off_h, off_l, idx;
    if (i < 8192) {                       // W1: K=64,  N=128
        int k = i >> 7, n = i & 127;
        w = W1[i]; idx = frag_off(n, k, 1024);  off_h = W1H; off_l = W1L;
    } else if (i < 40960) {               // W2: K=128, N=256
        int j = i - 8192;
        int k = j >> 8, n = j & 255;
        w = W2[j]; idx = frag_off(n, k, 2048);  off_h = W2H; off_l = W2L;
    } else if (i < 73728) {               // W3: K=256, N=128
        int j = i - 40960;
        int k = j >> 7, n = j & 127;
        w = W3[j]; idx = frag_off(n, k, 4096);  off_h = W3H; off_l = W3L;
    } else return;
    __hip_bfloat16 hb = __float2bfloat16(w);
    float hf = __bfloat162float(hb);
    __hip_bfloat16 lb = __float2bfloat16(w - hf);
    wext[off_h + idx] = *(ushort_t*)&hb;
    wext[off_l + idx] = *(ushort_t*)&lb;
}

// ---------------------------------------------------------------------------
__global__ __launch_bounds__(512) void head_kernel(
    const float* __restrict__ partial, const float* __restrict__ Wf,
    const float* __restrict__ bf, const float* __restrict__ Wc,
    const float* __restrict__ bc, float* __restrict__ dout)
{
    __shared__ float gfs[128];
    __shared__ float feats[512];
    int b = blockIdx.x, t = threadIdx.x;
    if (t < 128) {
        const float* p = partial + (size_t)b * (8 * 128);
        float s = 0.f;
        #pragma unroll
        for (int tt = 0; tt < 8; ++tt) s += p[tt * 128 + t];
        s *= (1.0f / 468.0f);
        gfs[t] = s;
        dout[65792 + b * 128 + t] = s;       // graph_features
    }
    __syncthreads();
    float a = bf[t];
    for (int k = 0; k < 128; ++k) a += gfs[k] * Wf[k * 512 + t];
    a = fmaxf(a, 0.f);
    dout[256 + b * 512 + t] = a;             // features
    feats[t] = a;
    __syncthreads();
    if (t < 64) {
        float s0 = 0.f, s1 = 0.f;
        for (int c = t; c < 512; c += 64) {
            float f = feats[c];
            s0 += f * Wc[c * 2 + 0];
            s1 += f * Wc[c * 2 + 1];
        }
        #pragma unroll
        for (int off = 32; off; off >>= 1) {
            s0 += __shfl_down(s0, off);
            s1 += __shfl_down(s1, off);
        }
        if (t == 0) {
            dout[b * 2 + 0] = s0 + bc[0];
            dout[b * 2 + 1] = s1 + bc[1];
        }
    }
}

// ---------------------------------------------------------------------------
extern "C" void kernel_launch(void* const* d_in, const int* in_sizes, int n_in,
                              void* d_out, int out_size, void* d_ws, size_t ws_size,
                              hipStream_t stream)
{
    const float* landmarks = (const float*)d_in[0];
    const float* W_enc     = (const float*)d_in[1];
    const float* b_enc     = (const float*)d_in[2];
    const float* W1        = (const float*)d_in[3];
    const float* b1        = (const float*)d_in[4];
    const float* W2        = (const float*)d_in[5];
    const float* b2        = (const float*)d_in[6];
    const float* W3        = (const float*)d_in[7];
    const float* b3        = (const float*)d_in[8];
    const float* W_fus     = (const float*)d_in[9];
    const float* b_fus     = (const float*)d_in[10];
    const float* W_cls     = (const float*)d_in[11];
    const float* b_cls     = (const float*)d_in[12];
    float* out = (float*)d_out;

    char* ws = (char*)d_ws;
    ushort_t* wext = (ushort_t*)(ws + 0);        // 294,912 B
    float* partial = (float*)(ws + 294912);      // 524,288 B

    wconv<<<288, 256, 0, stream>>>(W1, W2, W3, wext);
    fused2<<<dim3(8, 64), 1024, 0, stream>>>(
        landmarks, wext, W_enc, b_enc, b1, b2, b3, partial);
    head_kernel<<<128, 512, 0, stream>>>(partial, W_fus, b_fus, W_cls, b_cls, out);
}

// Round 21
// 67.954 us; speedup vs baseline: 1.8866x; 1.8866x over previous
//
#include <hip/hip_runtime.h>
#include <hip/hip_bf16.h>

typedef __bf16 bf16x8 __attribute__((ext_vector_type(8)));
typedef float  f32x4  __attribute__((ext_vector_type(4)));
typedef unsigned short ushort_t;

#define NN 468

// wext element offsets (ushort), fragment-major planes (NOT swizzled)
#define W1H 0
#define W1L 8192
#define W2H 16384
#define W2L 49152
#define W3H 81920
#define W3L 114688

// ---- LDS layout (64-row tile, hand-overlaid; total 78,752 B) --------------
// X1 [100][68]f32=27200 @0 | X2 [82][132]f32=43296 @0   (time-overlaid)
// Y1 @32096 (2x14336) | Y2 @27200 (2x24576 full-K) | Y3 @43296 (2x16384)
// lmst @76352 (1416) | dtab @77768 (472) | pool @78240 (512)
// Pairwise-live: {X1,Y2} ends 27200<=27200 OK via time-split; {X2,Y3} same;
// Y1 disjoint from X1. (R16-verified overlays; X0 removed this round.)
#define L_Y1   32096
#define L_Y2   27200
#define L_Y3   43296
#define L_LM   76352
#define L_DTAB 77768
#define L_POOL 78240

#define MFMA3(d, ah, al, wh, wl)                                        \
    d = __builtin_amdgcn_mfma_f32_16x16x32_bf16(ah, wh, d, 0, 0, 0);    \
    d = __builtin_amdgcn_mfma_f32_16x16x32_bf16(ah, wl, d, 0, 0, 0);    \
    d = __builtin_amdgcn_mfma_f32_16x16x32_bf16(al, wh, d, 0, 0, 0);

// ---------------------------------------------------------------------------
__device__ __forceinline__ void pack_split4(const float* y,
                                            ushort_t* hdst, ushort_t* ldst) {
    ushort_t h[4], l[4];
    #pragma unroll
    for (int j = 0; j < 4; ++j) {
        __hip_bfloat16 hb = __float2bfloat16(y[j]);
        float hf = __bfloat162float(hb);
        __hip_bfloat16 lb = __float2bfloat16(y[j] - hf);
        h[j] = *(ushort_t*)&hb; l[j] = *(ushort_t*)&lb;
    }
    uint2 hv = make_uint2((unsigned)h[0] | ((unsigned)h[1] << 16),
                          (unsigned)h[2] | ((unsigned)h[3] << 16));
    uint2 lv = make_uint2((unsigned)l[0] | ((unsigned)l[1] << 16),
                          (unsigned)l[2] | ((unsigned)l[3] << 16));
    *(uint2*)hdst = hv;
    *(uint2*)ldst = lv;
}

__device__ __forceinline__ int frag_off(int r, int k, int K16) {
    return (r >> 4) * K16 + (k >> 5) * 512 + ((k >> 3) & 3) * 128
         + (r & 15) * 8 + (k & 7);
}

// swizzled Y-plane offset (LDS): unit' = q*16 + ((r ^ 2q) & 15)
__device__ __forceinline__ int ywoff(int r, int k4, int K16) {
    int q = (k4 >> 3) & 3;
    int u = q * 16 + (((r & 15) ^ (q << 1)) & 15);
    return (r >> 4) * K16 + (k4 >> 5) * 512 + u * 8 + (k4 & 7);
}

// ---------------------------------------------------------------------------
// fused: full 3-layer GCN chain for one (64-row tile, batch) in LDS.
// 512 threads = 8 waves (wm = w&1 over m, wn = w>>1 over n).
// Frames (dtab[t] = dinv(r0-27+t), t<118):
//   X0 l0 (virtual, in-reg): gr = r0-27+l0 (0..117)
//   Y1/X1 lr1 : gr = r0-18+lr1 (0..99, Y1 padded to 112 = 7 tiles)
//   Y2/X2 lr2 : gr = r0-9+lr2  (0..81, Y2 padded to 96 = 6 tiles)
//   Y3    lr3 : gr = r0+lr3    (0..63, 4 tiles)
// R20 change vs R16: encoder fused INTO band1 in registers (z[31]/slice;
// lmst+dtab reads are wave-broadcast) — removes enc phase, X0 buffer, and
// one barrier. All other phases byte-identical to R16 (66.8us verified).
// launch_bounds(512,4): 128-reg cap — NEVER raise min-waves (R10/R13 spill).
// ---------------------------------------------------------------------------
__global__ __launch_bounds__(512, 4) void fused(
    const float* __restrict__ Lm, const ushort_t* __restrict__ wext,
    const float* __restrict__ We, const float* __restrict__ be,
    const float* __restrict__ b1, const float* __restrict__ b2,
    const float* __restrict__ b3, float* __restrict__ partial)
{
    __shared__ __align__(16) char lds[78752];
    float*    X    = (float*)(lds);            // X1 / X2 overlaid
    ushort_t* Y1h  = (ushort_t*)(lds + L_Y1);  ushort_t* Y1l = Y1h + 7168;
    ushort_t* Y2h  = (ushort_t*)(lds + L_Y2);  ushort_t* Y2l = Y2h + 12288;
    ushort_t* Y3h  = (ushort_t*)(lds + L_Y3);  ushort_t* Y3l = Y3h + 8192;
    float*    lmst = (float*)(lds + L_LM);
    float*    dtab = (float*)(lds + L_DTAB);
    float*    pool = (float*)(lds + L_POOL);

    const int tid  = threadIdx.x;
    const int lane = tid & 63;
    const int wave = tid >> 6;                 // 0..7
    const int wm = wave & 1, wn = wave >> 1;   // wn in 0..3
    const int l15 = lane & 15, lg = lane >> 4;
    const int lswz = (lane & 48) + (((lane & 15) ^ ((lane >> 4) << 1)) & 15);
    const int rt = blockIdx.x, b = blockIdx.y;
    const int r0 = rt * 64;

    // ---------------- stage: dinv table, landmarks, pool init -------------
    if (tid < 118) {
        int ri = r0 - 27 + tid;
        float dv = 0.f;
        if (ri >= 0 && ri < NN) {
            int lo = ri - 9; if (lo < 0) lo = 0;
            int hi = ri + 9; if (hi > NN - 1) hi = NN - 1;
            dv = 1.0f / sqrtf((float)(hi - lo + 1));
        }
        dtab[tid] = dv;
    }
    if (tid < 354) {
        int g = (r0 - 27) * 3 + tid;
        lmst[tid] = (g >= 0 && g < NN * 3) ? Lm[(size_t)b * (NN * 3) + g] : 0.f;
    }
    if (tid < 128) pool[tid] = 0.f;
    __syncthreads();

    // ------- band1 (encoder fused, in-register): -> Y1 [100 rows][64] ------
    {
        const int c = lane;                    // column 0..63
        const int s = wave;                    // slice: rows s*13 .. s*13+12
        const float w0 = We[c], w1 = We[64 + c], w2 = We[128 + c], bk = be[c];
        float z[31];
        #pragma unroll
        for (int j = 0; j < 31; ++j) {
            int l0 = s * 13 + j;               // virtual X0 row (0..121)
            float v = 0.f;
            if (l0 < 118) {
                // lmst/dtab reads are wave-uniform (same l0 across lanes): broadcast
                float x = bk + lmst[l0*3]*w0 + lmst[l0*3+1]*w1 + lmst[l0*3+2]*w2;
                v = x * dtab[l0];              // dtab=0 masks OOR rows
            }
            z[j] = v;
        }
        float ws = 0.f;
        #pragma unroll
        for (int j = 0; j < 19; ++j) ws += z[j];
        #pragma unroll
        for (int rr = 0; rr < 13; ++rr) {
            if (rr) ws += z[rr + 18] - z[rr - 1];
            int lr = s * 13 + rr;
            if (lr < 100) {
                float y = ws * dtab[lr + 9];
                __hip_bfloat16 hb = __float2bfloat16(y);
                float hf = __bfloat162float(hb);
                __hip_bfloat16 lb = __float2bfloat16(y - hf);
                int off = ywoff(lr, c, 1024);
                Y1h[off] = *(ushort_t*)&hb;
                Y1l[off] = *(ushort_t*)&lb;
            }
        }
        if (tid < 192) {                       // zero pad rows 100..111
            int row = 100 + (tid >> 4);
            int c4  = (tid & 15) << 2;
            int off = ywoff(row, c4, 1024);
            *(uint2*)(Y1h + off) = make_uint2(0, 0);
            *(uint2*)(Y1l + off) = make_uint2(0, 0);
        }
    }
    __syncthreads();

    // ---------------- GEMM1: Y1(7 tiles) @ W1 ------------------------------
    // m: t = wm*4+mt clamp 6 (dup within-wave, benign); n: ntile = nt*4+wn
    f32x4 acc1[4][2] = {};
    __builtin_amdgcn_s_setprio(1);
    #pragma unroll
    for (int kt = 0; kt < 2; ++kt) {
        bf16x8 a[4][2];
        #pragma unroll
        for (int mt = 0; mt < 4; ++mt) {
            int t = wm*4 + mt; if (t > 6) t = 6;
            int off = t * 1024 + kt * 512 + lswz * 8;
            a[mt][0] = *(const bf16x8*)(Y1h + off);
            a[mt][1] = *(const bf16x8*)(Y1l + off);
        }
        #pragma unroll
        for (int nt = 0; nt < 2; ++nt) {
            int woff = (nt*4 + wn) * 1024 + kt * 512 + lane * 8;
            bf16x8 wh = *(const bf16x8*)(wext + W1H + woff);
            bf16x8 wl = *(const bf16x8*)(wext + W1L + woff);
            #pragma unroll
            for (int mt = 0; mt < 4; ++mt) {
                MFMA3(acc1[mt][nt], a[mt][0], a[mt][1], wh, wl);
            }
        }
    }
    __builtin_amdgcn_s_setprio(0);
    // no barrier needed: epi1(0) writes X1 [0,27200) — disjoint from Y1 @32096

    // ------- kc loop: epi1(kc) -> X1 -> band2(kc) -> Y2 cols kc*64.. -------
    #pragma unroll
    for (int kc = 0; kc < 2; ++kc) {
        // epi1(kc): acc1[:,kc] -> X1[100][68] premult
        #pragma unroll
        for (int mt = 0; mt < 4; ++mt) {
            int t = wm*4 + mt; if (t > 6) t = 6;
            int gcol = (kc*4 + wn)*16 + l15;
            int cl   = wn*16 + l15;
            float bv = b1[gcol];
            #pragma unroll
            for (int r = 0; r < 4; ++r) {
                int lr1 = t*16 + lg*4 + r;
                if (lr1 < 100)
                    X[lr1*68 + cl] =
                        dtab[lr1 + 9] * fmaxf(acc1[mt][kc][r] + bv, 0.f);
            }
        }
        __syncthreads();   // X1 ready; (kc=0) also fences Y1 reads vs Y2 writes

        // band2(kc): X1 -> Y2 [82 rows][k-cols kc*64..+64), pad rows to 96
        {
            const int c4   = (tid & 15) << 2;
            const int base = (tid >> 4) * 3;   // 32 groups x 3 rows = 96
            f32x4 ws = {};
            if (base < 82) {
                #pragma unroll
                for (int d = 0; d < 19; ++d)
                    ws += *(const f32x4*)(X + (base + d) * 68 + c4);
            }
            #pragma unroll
            for (int rr = 0; rr < 3; ++rr) {
                int row = base + rr;
                if (row < 96) {
                    float y4[4] = {0.f, 0.f, 0.f, 0.f};
                    if (row < 82) {
                        if (rr) ws += *(const f32x4*)(X + (row + 18) * 68 + c4)
                                    - *(const f32x4*)(X + (row - 1)  * 68 + c4);
                        float dv = dtab[row + 18];
                        y4[0] = ws[0]*dv; y4[1] = ws[1]*dv;
                        y4[2] = ws[2]*dv; y4[3] = ws[3]*dv;
                    }
                    int off = ywoff(row, kc*64 + c4, 2048);
                    pack_split4(y4, Y2h + off, Y2l + off);
                }
            }
        }
        __syncthreads();   // Y2 chunk ready; X1 reads done (epi1(1) may rewrite)
    }

    // ---------------- GEMM2: Y2(6 tiles, K=128) @ W2 — one fat phase -------
    // acc1 is DEAD here: no accumulator coexistence, no spill (R16-verified).
    f32x4 acc2[3][4] = {};
    __builtin_amdgcn_s_setprio(1);
    #pragma unroll
    for (int kt = 0; kt < 4; ++kt) {
        bf16x8 a[3][2];
        #pragma unroll
        for (int mt = 0; mt < 3; ++mt) {
            int off = (wm*3 + mt) * 2048 + kt * 512 + lswz * 8;
            a[mt][0] = *(const bf16x8*)(Y2h + off);
            a[mt][1] = *(const bf16x8*)(Y2l + off);
        }
        #pragma unroll
        for (int nt = 0; nt < 4; ++nt) {
            int woff = (nt*4 + wn) * 2048 + kt * 512 + lane * 8;
            bf16x8 wh = *(const bf16x8*)(wext + W2H + woff);
            bf16x8 wl = *(const bf16x8*)(wext + W2L + woff);
            #pragma unroll
            for (int mt = 0; mt < 3; ++mt) {
                MFMA3(acc2[mt][nt], a[mt][0], a[mt][1], wh, wl);
            }
        }
    }
    __builtin_amdgcn_s_setprio(0);
    __syncthreads();   // all Y2 reads done before epi2(0) writes X2 (overlap)

    // ------- nc loop: [GEMM3(nc-1) ∥] epi2 -> X2 -> band3 -> Y3 -> GEMM3 ---
    f32x4 acc3[2][2] = {};
    #pragma unroll
    for (int nc = 0; nc < 2; ++nc) {
        if (nc == 1) {
            __builtin_amdgcn_s_setprio(1);
            #pragma unroll
            for (int kt = 0; kt < 4; ++kt) {
                bf16x8 a0[2], a1[2];
                #pragma unroll
                for (int mt = 0; mt < 2; ++mt) {
                    int aoff = (wm*2 + mt) * 2048 + kt * 512 + lswz * 8;
                    a0[mt] = *(const bf16x8*)(Y3h + aoff);
                    a1[mt] = *(const bf16x8*)(Y3l + aoff);
                }
                #pragma unroll
                for (int nt = 0; nt < 2; ++nt) {
                    int woff = (nt*4 + wn) * 4096 + (0*4 + kt) * 512 + lane * 8;
                    bf16x8 wh = *(const bf16x8*)(wext + W3H + woff);
                    bf16x8 wl = *(const bf16x8*)(wext + W3L + woff);
                    #pragma unroll
                    for (int mt = 0; mt < 2; ++mt) {
                        MFMA3(acc3[mt][nt], a0[mt], a1[mt], wh, wl);
                    }
                }
            }
            __builtin_amdgcn_s_setprio(0);
        }
        // epi2(nc): acc2 n-chunk -> X2[82][132] premult
        #pragma unroll
        for (int mt = 0; mt < 3; ++mt)
        #pragma unroll
        for (int q = 0; q < 2; ++q) {
            int gcol = ((nc*2 + q)*4 + wn)*16 + l15;
            int cl   = (q*4 + wn)*16 + l15;
            float bv = b2[gcol];
            #pragma unroll
            for (int r = 0; r < 4; ++r) {
                int lr2 = (wm*3 + mt)*16 + lg*4 + r;
                if (lr2 < 82)
                    X[lr2*132 + cl] =
                        dtab[lr2 + 18] * fmaxf(acc2[mt][nc*2 + q][r] + bv, 0.f);
            }
        }
        __syncthreads();

        // band3(nc): X2 -> Y3 [64 rows][128]
        {
            const int c4   = (tid & 31) << 2;  // 128 cols
            const int base = (tid >> 5) * 4;   // 16 groups x 4 rows
            f32x4 ws = {};
            #pragma unroll
            for (int d = 0; d < 19; ++d)
                ws += *(const f32x4*)(X + (base + d) * 132 + c4);
            #pragma unroll
            for (int rr = 0; rr < 4; ++rr) {
                int row = base + rr;
                if (rr) ws += *(const f32x4*)(X + (row + 18) * 132 + c4)
                            - *(const f32x4*)(X + (row - 1)  * 132 + c4);
                float dv = dtab[row + 27];
                float y4[4] = {ws[0]*dv, ws[1]*dv, ws[2]*dv, ws[3]*dv};
                int off = ywoff(row, c4, 2048);
                pack_split4(y4, Y3h + off, Y3l + off);
            }
        }
        __syncthreads();
    }

    // ---- trailing GEMM3(nc=1) ----
    __builtin_amdgcn_s_setprio(1);
    #pragma unroll
    for (int kt = 0; kt < 4; ++kt) {
        bf16x8 a0[2], a1[2];
        #pragma unroll
        for (int mt = 0; mt < 2; ++mt) {
            int aoff = (wm*2 + mt) * 2048 + kt * 512 + lswz * 8;
            a0[mt] = *(const bf16x8*)(Y3h + aoff);
            a1[mt] = *(const bf16x8*)(Y3l + aoff);
        }
        #pragma unroll
        for (int nt = 0; nt < 2; ++nt) {
            int woff = (nt*4 + wn) * 4096 + (1*4 + kt) * 512 + lane * 8;
            bf16x8 wh = *(const bf16x8*)(wext + W3H + woff);
            bf16x8 wl = *(const bf16x8*)(wext + W3L + woff);
            #pragma unroll
            for (int mt = 0; mt < 2; ++mt) {
                MFMA3(acc3[mt][nt], a0[mt], a1[mt], wh, wl);
            }
        }
    }
    __builtin_amdgcn_s_setprio(0);

    // ---------------- pool: column sums of relu(acc3 + b3) -----------------
    #pragma unroll
    for (int nt = 0; nt < 2; ++nt) {
        int g_t = nt*4 + wn;
        float bv = b3[g_t*16 + l15];
        float cs = 0.f;
        #pragma unroll
        for (int mt = 0; mt < 2; ++mt)
        #pragma unroll
        for (int r = 0; r < 4; ++r) {
            int gr = r0 + (wm*2 + mt)*16 + lg*4 + r;
            if (gr < NN) cs += fmaxf(acc3[mt][nt][r] + bv, 0.f);
        }
        cs += __shfl_xor(cs, 16);
        cs += __shfl_xor(cs, 32);
        if (lane < 16) atomicAdd(&pool[g_t*16 + lane], cs);
    }
    __syncthreads();
    if (tid < 128) partial[((size_t)b * 8 + rt) * 128 + tid] = pool[tid];
}

// ---------------------------------------------------------------------------
// wconv: W fp32 [K][N] -> bf16 hi/lo planes, fragment layout (unswizzled)
// ---------------------------------------------------------------------------
__global__ __launch_bounds__(256) void wconv(
    const float* __restrict__ W1, const float* __restrict__ W2,
    const float* __restrict__ W3, ushort_t* __restrict__ wext)
{
    int i = blockIdx.x * 256 + threadIdx.x;
    float w; int off_h, off_l, idx;
    if (i < 8192) {                       // W1: K=64,  N=128
        int k = i >> 7, n = i & 127;
        w = W1[i]; idx = frag_off(n, k, 1024);  off_h = W1H; off_l = W1L;
    } else if (i < 40960) {               // W2: K=128, N=256
        int j = i - 8192;
        int k = j >> 8, n = j & 255;
        w = W2[j]; idx = frag_off(n, k, 2048);  off_h = W2H; off_l = W2L;
    } else if (i < 73728) {               // W3: K=256, N=128
        int j = i - 40960;
        int k = j >> 7, n = j & 127;
        w = W3[j]; idx = frag_off(n, k, 4096);  off_h = W3H; off_l = W3L;
    } else return;
    __hip_bfloat16 hb = __float2bfloat16(w);
    float hf = __bfloat162float(hb);
    __hip_bfloat16 lb = __float2bfloat16(w - hf);
    wext[off_h + idx] = *(ushort_t*)&hb;
    wext[off_l + idx] = *(ushort_t*)&lb;
}

// ---------------------------------------------------------------------------
// head: gf = mean-pool reduce; features = relu(gf@Wf+bf); out = feats@Wc+bc
// ---------------------------------------------------------------------------
__global__ __launch_bounds__(512) void head_kernel(
    const float* __restrict__ partial, const float* __restrict__ Wf,
    const float* __restrict__ bf, const float* __restrict__ Wc,
    const float* __restrict__ bc, float* __restrict__ dout)
{
    __shared__ float gfs[128];
    __shared__ float feats[512];
    int b = blockIdx.x, t = threadIdx.x;
    if (t < 128) {
        const float* p = partial + (size_t)b * (8 * 128);
        float s = 0.f;
        #pragma unroll
        for (int tt = 0; tt < 8; ++tt) s += p[tt * 128 + t];
        s *= (1.0f / 468.0f);
        gfs[t] = s;
        dout[65792 + b * 128 + t] = s;       // graph_features
    }
    __syncthreads();
    float a = bf[t];
    for (int k = 0; k < 128; ++k) a += gfs[k] * Wf[k * 512 + t];
    a = fmaxf(a, 0.f);
    dout[256 + b * 512 + t] = a;             // features
    feats[t] = a;
    __syncthreads();
    if (t < 64) {
        float s0 = 0.f, s1 = 0.f;
        for (int c = t; c < 512; c += 64) {
            float f = feats[c];
            s0 += f * Wc[c * 2 + 0];
            s1 += f * Wc[c * 2 + 1];
        }
        #pragma unroll
        for (int off = 32; off; off >>= 1) {
            s0 += __shfl_down(s0, off);
            s1 += __shfl_down(s1, off);
        }
        if (t == 0) {
            dout[b * 2 + 0] = s0 + bc[0];
            dout[b * 2 + 1] = s1 + bc[1];
        }
    }
}

// ---------------------------------------------------------------------------
extern "C" void kernel_launch(void* const* d_in, const int* in_sizes, int n_in,
                              void* d_out, int out_size, void* d_ws, size_t ws_size,
                              hipStream_t stream)
{
    const float* landmarks = (const float*)d_in[0];
    const float* W_enc     = (const float*)d_in[1];
    const float* b_enc     = (const float*)d_in[2];
    const float* W1        = (const float*)d_in[3];
    const float* b1        = (const float*)d_in[4];
    const float* W2        = (const float*)d_in[5];
    const float* b2        = (const float*)d_in[6];
    const float* W3        = (const float*)d_in[7];
    const float* b3        = (const float*)d_in[8];
    const float* W_fus     = (const float*)d_in[9];
    const float* b_fus     = (const float*)d_in[10];
    const float* W_cls     = (const float*)d_in[11];
    const float* b_cls     = (const float*)d_in[12];
    float* out = (float*)d_out;

    char* ws = (char*)d_ws;
    ushort_t* wext = (ushort_t*)(ws + 0);        // 294,912 B
    float* partial = (float*)(ws + 294912);      // 524,288 B

    wconv<<<288, 256, 0, stream>>>(W1, W2, W3, wext);
    fused<<<dim3(8, 128), 512, 0, stream>>>(
        landmarks, wext, W_enc, b_enc, b1, b2, b3, partial);
    head_kernel<<<128, 512, 0, stream>>>(partial, W_fus, b_fus, W_cls, b_cls, out);
}

// Round 22
// 66.800 us; speedup vs baseline: 1.9192x; 1.0173x over previous
//
#include <hip/hip_runtime.h>
#include <hip/hip_bf16.h>

typedef __bf16 bf16x8 __attribute__((ext_vector_type(8)));
typedef float  f32x4  __attribute__((ext_vector_type(4)));
typedef unsigned short ushort_t;

#define NN 468

// wext element offsets (ushort), fragment-major planes (NOT swizzled)
#define W1H 0
#define W1L 8192
#define W2H 16384
#define W2L 49152
#define W3H 81920
#define W3L 114688

// ---- LDS layout (64-row tile, hand-overlaid; total 78,752 B -> 2 blk/CU) --
// X0 [118][68]f32 = 32096  @0      (enc..band1)
// X1 [100][68]f32 = 27200  @0      (epi1..band2)
// X2 [82][132]f32 = 43296  @0      (epi2..band3)
// Y1  2 x 14336B           @32096  (band1..GEMM1)   [32096,60768)
// Y2  2 x 24576B (full K)  @27200  (band2..GEMM2)   [27200,76352)
// Y3  2 x 16384B           @43296  (band3..GEMM3)   [43296,76064)
// lmst 1416B @76352 | dtab 472B @77768 | pool 512B @78240
// Pairwise-live: {X0,Y1} {X1,Y2} {X2,Y3} all disjoint; Y overlaps are
// time-separated by the phase barriers (Y1 dead at band2, Y2 dead at epi2).
#define L_Y1   32096
#define L_Y2   27200
#define L_Y3   43296
#define L_LM   76352
#define L_DTAB 77768
#define L_POOL 78240

#define MFMA3(d, ah, al, wh, wl)                                        \
    d = __builtin_amdgcn_mfma_f32_16x16x32_bf16(ah, wh, d, 0, 0, 0);    \
    d = __builtin_amdgcn_mfma_f32_16x16x32_bf16(ah, wl, d, 0, 0, 0);    \
    d = __builtin_amdgcn_mfma_f32_16x16x32_bf16(al, wh, d, 0, 0, 0);

// ---------------------------------------------------------------------------
__device__ __forceinline__ void pack_split4(const float* y,
                                            ushort_t* hdst, ushort_t* ldst) {
    ushort_t h[4], l[4];
    #pragma unroll
    for (int j = 0; j < 4; ++j) {
        __hip_bfloat16 hb = __float2bfloat16(y[j]);
        float hf = __bfloat162float(hb);
        __hip_bfloat16 lb = __float2bfloat16(y[j] - hf);
        h[j] = *(ushort_t*)&hb; l[j] = *(ushort_t*)&lb;
    }
    uint2 hv = make_uint2((unsigned)h[0] | ((unsigned)h[1] << 16),
                          (unsigned)h[2] | ((unsigned)h[3] << 16));
    uint2 lv = make_uint2((unsigned)l[0] | ((unsigned)l[1] << 16),
                          (unsigned)l[2] | ((unsigned)l[3] << 16));
    *(uint2*)hdst = hv;
    *(uint2*)ldst = lv;
}

// unswizzled fragment offset (W planes in global memory)
__device__ __forceinline__ int frag_off(int r, int k, int K16) {
    return (r >> 4) * K16 + (k >> 5) * 512 + ((k >> 3) & 3) * 128
         + (r & 15) * 8 + (k & 7);
}

// swizzled Y-plane offset (LDS): unit' = q*16 + ((r ^ 2q) & 15)
__device__ __forceinline__ int ywoff(int r, int k4, int K16) {
    int q = (k4 >> 3) & 3;
    int u = q * 16 + (((r & 15) ^ (q << 1)) & 15);
    return (r >> 4) * K16 + (k4 >> 5) * 512 + u * 8 + (k4 & 7);
}

// ---------------------------------------------------------------------------
// fused: full 3-layer GCN chain for one (64-row tile, batch) in LDS.
// 512 threads = 8 waves (wm = w&1 over m, wn = w>>1 over n).
// Frames (dtab[t] = dinv(r0-27+t), t<118):
//   X0 row l0 : gr = r0-27+l0  (0..117)
//   Y1/X1 lr1 : gr = r0-18+lr1 (0..99, Y1 padded to 112 = 7 tiles)
//   Y2/X2 lr2 : gr = r0-9+lr2  (0..81, Y2 padded to 96 = 6 tiles)
//   Y3    lr3 : gr = r0+lr3    (0..63, 4 tiles)
// Y2 holds FULL K=128 so GEMM2 runs as one phase AFTER acc1 dies — no
// accumulator coexistence (R15's spill). BEST MEASURED: 66.8us (R16).
// launch_bounds(512,4): cap 128 regs — NEVER raise min-waves (R10/R13 spill).
// ---------------------------------------------------------------------------
__global__ __launch_bounds__(512, 4) void fused(
    const float* __restrict__ Lm, const ushort_t* __restrict__ wext,
    const float* __restrict__ We, const float* __restrict__ be,
    const float* __restrict__ b1, const float* __restrict__ b2,
    const float* __restrict__ b3, float* __restrict__ partial)
{
    __shared__ __align__(16) char lds[78752];
    float*    X    = (float*)(lds);            // X0 / X1 / X2 overlaid
    ushort_t* Y1h  = (ushort_t*)(lds + L_Y1);  ushort_t* Y1l = Y1h + 7168;
    ushort_t* Y2h  = (ushort_t*)(lds + L_Y2);  ushort_t* Y2l = Y2h + 12288;
    ushort_t* Y3h  = (ushort_t*)(lds + L_Y3);  ushort_t* Y3l = Y3h + 8192;
    float*    lmst = (float*)(lds + L_LM);
    float*    dtab = (float*)(lds + L_DTAB);
    float*    pool = (float*)(lds + L_POOL);

    const int tid  = threadIdx.x;
    const int lane = tid & 63;
    const int wave = tid >> 6;                 // 0..7
    const int wm = wave & 1, wn = wave >> 1;   // wn in 0..3
    const int l15 = lane & 15, lg = lane >> 4;
    const int lswz = (lane & 48) + (((lane & 15) ^ ((lane >> 4) << 1)) & 15);
    const int rt = blockIdx.x, b = blockIdx.y;
    const int r0 = rt * 64;

    // ---------------- stage: dinv table, landmarks, pool init -------------
    if (tid < 118) {
        int ri = r0 - 27 + tid;
        float dv = 0.f;
        if (ri >= 0 && ri < NN) {
            int lo = ri - 9; if (lo < 0) lo = 0;
            int hi = ri + 9; if (hi > NN - 1) hi = NN - 1;
            dv = 1.0f / sqrtf((float)(hi - lo + 1));
        }
        dtab[tid] = dv;
    }
    if (tid < 354) {
        int g = (r0 - 27) * 3 + tid;
        lmst[tid] = (g >= 0 && g < NN * 3) ? Lm[(size_t)b * (NN * 3) + g] : 0.f;
    }
    if (tid < 128) pool[tid] = 0.f;
    __syncthreads();

    // ---------------- enc: X0[118][68] = enc(row) * dinv -------------------
    {
        const int c = tid & 63;
        const float w0 = We[c], w1 = We[64 + c], w2 = We[128 + c], bk = be[c];
        for (int l0 = tid >> 6; l0 < 118; l0 += 8) {
            float x = bk + lmst[l0*3]*w0 + lmst[l0*3+1]*w1 + lmst[l0*3+2]*w2;
            X[l0 * 68 + c] = x * dtab[l0];
        }
    }
    __syncthreads();    // X0 ready; lmst dead

    // ---------------- band1: X0 -> Y1 [100 rows][64], pad to 112 -----------
    {
        const int c4 = (tid & 15) << 2;
        const int base = (tid >> 4) * 4;       // 32 groups x 4 rows
        if (base < 100) {
            f32x4 ws = {};
            #pragma unroll
            for (int d = 0; d < 19; ++d)
                ws += *(const f32x4*)(X + (base + d) * 68 + c4);
            #pragma unroll
            for (int rr = 0; rr < 4; ++rr) {
                int row = base + rr;
                if (rr) ws += *(const f32x4*)(X + (row + 18) * 68 + c4)
                            - *(const f32x4*)(X + (row - 1)  * 68 + c4);
                float dv = dtab[row + 9];
                float y4[4] = {ws[0]*dv, ws[1]*dv, ws[2]*dv, ws[3]*dv};
                int off = ywoff(row, c4, 1024);
                pack_split4(y4, Y1h + off, Y1l + off);
            }
        } else if (base < 112) {               // zero pad rows 100..111
            float z4[4] = {0.f, 0.f, 0.f, 0.f};
            #pragma unroll
            for (int rr = 0; rr < 4; ++rr) {
                int row = base + rr;
                if (row < 112) {
                    int off = ywoff(row, c4, 1024);
                    pack_split4(z4, Y1h + off, Y1l + off);
                }
            }
        }
    }
    __syncthreads();

    // ---------------- GEMM1: Y1(7 tiles) @ W1 ------------------------------
    // m: t = wm*4+mt clamp 6 (dup within-wave, benign); n: ntile = nt*4+wn
    f32x4 acc1[4][2] = {};
    __builtin_amdgcn_s_setprio(1);
    #pragma unroll
    for (int kt = 0; kt < 2; ++kt) {
        bf16x8 a[4][2];
        #pragma unroll
        for (int mt = 0; mt < 4; ++mt) {
            int t = wm*4 + mt; if (t > 6) t = 6;
            int off = t * 1024 + kt * 512 + lswz * 8;
            a[mt][0] = *(const bf16x8*)(Y1h + off);
            a[mt][1] = *(const bf16x8*)(Y1l + off);
        }
        #pragma unroll
        for (int nt = 0; nt < 2; ++nt) {
            int woff = (nt*4 + wn) * 1024 + kt * 512 + lane * 8;
            bf16x8 wh = *(const bf16x8*)(wext + W1H + woff);
            bf16x8 wl = *(const bf16x8*)(wext + W1L + woff);
            #pragma unroll
            for (int mt = 0; mt < 4; ++mt) {
                MFMA3(acc1[mt][nt], a[mt][0], a[mt][1], wh, wl);
            }
        }
    }
    __builtin_amdgcn_s_setprio(0);
    // no barrier needed: epi1(0) writes X1 (region disjoint from Y1)

    // ------- kc loop: epi1(kc) -> X1 -> band2(kc) -> Y2 cols kc*64.. -------
    #pragma unroll
    for (int kc = 0; kc < 2; ++kc) {
        // epi1(kc): acc1[:,kc] -> X1[100][68] premult
        #pragma unroll
        for (int mt = 0; mt < 4; ++mt) {
            int t = wm*4 + mt; if (t > 6) t = 6;
            int gcol = (kc*4 + wn)*16 + l15;
            int cl   = wn*16 + l15;
            float bv = b1[gcol];
            #pragma unroll
            for (int r = 0; r < 4; ++r) {
                int lr1 = t*16 + lg*4 + r;
                if (lr1 < 100)
                    X[lr1*68 + cl] =
                        dtab[lr1 + 9] * fmaxf(acc1[mt][kc][r] + bv, 0.f);
            }
        }
        __syncthreads();   // X1 ready; (kc=0) also fences Y1 reads vs Y2 writes

        // band2(kc): X1 -> Y2 [82 rows][k-cols kc*64..+64), pad rows to 96
        {
            const int c4   = (tid & 15) << 2;
            const int base = (tid >> 4) * 3;   // 32 groups x 3 rows = 96
            f32x4 ws = {};
            if (base < 82) {
                #pragma unroll
                for (int d = 0; d < 19; ++d)
                    ws += *(const f32x4*)(X + (base + d) * 68 + c4);
            }
            #pragma unroll
            for (int rr = 0; rr < 3; ++rr) {
                int row = base + rr;
                if (row < 96) {
                    float y4[4] = {0.f, 0.f, 0.f, 0.f};
                    if (row < 82) {
                        if (rr) ws += *(const f32x4*)(X + (row + 18) * 68 + c4)
                                    - *(const f32x4*)(X + (row - 1)  * 68 + c4);
                        float dv = dtab[row + 18];
                        y4[0] = ws[0]*dv; y4[1] = ws[1]*dv;
                        y4[2] = ws[2]*dv; y4[3] = ws[3]*dv;
                    }
                    int off = ywoff(row, kc*64 + c4, 2048);
                    pack_split4(y4, Y2h + off, Y2l + off);
                }
            }
        }
        __syncthreads();   // Y2 chunk ready; X1 reads done (epi1(1) may rewrite)
    }

    // ---------------- GEMM2: Y2(6 tiles, K=128) @ W2 — one fat phase -------
    // acc1 is DEAD here: no accumulator coexistence, no spill.
    f32x4 acc2[3][4] = {};
    __builtin_amdgcn_s_setprio(1);
    #pragma unroll
    for (int kt = 0; kt < 4; ++kt) {
        bf16x8 a[3][2];
        #pragma unroll
        for (int mt = 0; mt < 3; ++mt) {
            int off = (wm*3 + mt) * 2048 + kt * 512 + lswz * 8;
            a[mt][0] = *(const bf16x8*)(Y2h + off);
            a[mt][1] = *(const bf16x8*)(Y2l + off);
        }
        #pragma unroll
        for (int nt = 0; nt < 4; ++nt) {
            int woff = (nt*4 + wn) * 2048 + kt * 512 + lane * 8;
            bf16x8 wh = *(const bf16x8*)(wext + W2H + woff);
            bf16x8 wl = *(const bf16x8*)(wext + W2L + woff);
            #pragma unroll
            for (int mt = 0; mt < 3; ++mt) {
                MFMA3(acc2[mt][nt], a[mt][0], a[mt][1], wh, wl);
            }
        }
    }
    __builtin_amdgcn_s_setprio(0);
    __syncthreads();   // all Y2 reads done before epi2(0) writes X2 (overlap!)

    // ------- nc loop: [GEMM3(nc-1) ∥] epi2 -> X2 -> band3 -> Y3 -> GEMM3 ---
    f32x4 acc3[2][2] = {};
    #pragma unroll
    for (int nc = 0; nc < 2; ++nc) {
        if (nc == 1) {
            __builtin_amdgcn_s_setprio(1);
            #pragma unroll
            for (int kt = 0; kt < 4; ++kt) {
                bf16x8 a0[2], a1[2];
                #pragma unroll
                for (int mt = 0; mt < 2; ++mt) {
                    int aoff = (wm*2 + mt) * 2048 + kt * 512 + lswz * 8;
                    a0[mt] = *(const bf16x8*)(Y3h + aoff);
                    a1[mt] = *(const bf16x8*)(Y3l + aoff);
                }
                #pragma unroll
                for (int nt = 0; nt < 2; ++nt) {
                    int woff = (nt*4 + wn) * 4096 + (0*4 + kt) * 512 + lane * 8;
                    bf16x8 wh = *(const bf16x8*)(wext + W3H + woff);
                    bf16x8 wl = *(const bf16x8*)(wext + W3L + woff);
                    #pragma unroll
                    for (int mt = 0; mt < 2; ++mt) {
                        MFMA3(acc3[mt][nt], a0[mt], a1[mt], wh, wl);
                    }
                }
            }
            __builtin_amdgcn_s_setprio(0);
        }
        // epi2(nc): acc2 n-chunk -> X2[82][132] premult
        #pragma unroll
        for (int mt = 0; mt < 3; ++mt)
        #pragma unroll
        for (int q = 0; q < 2; ++q) {
            int gcol = ((nc*2 + q)*4 + wn)*16 + l15;
            int cl   = (q*4 + wn)*16 + l15;
            float bv = b2[gcol];
            #pragma unroll
            for (int r = 0; r < 4; ++r) {
                int lr2 = (wm*3 + mt)*16 + lg*4 + r;
                if (lr2 < 82)
                    X[lr2*132 + cl] =
                        dtab[lr2 + 18] * fmaxf(acc2[mt][nc*2 + q][r] + bv, 0.f);
            }
        }
        __syncthreads();

        // band3(nc): X2 -> Y3 [64 rows][128]
        {
            const int c4   = (tid & 31) << 2;  // 128 cols
            const int base = (tid >> 5) * 4;   // 16 groups x 4 rows
            f32x4 ws = {};
            #pragma unroll
            for (int d = 0; d < 19; ++d)
                ws += *(const f32x4*)(X + (base + d) * 132 + c4);
            #pragma unroll
            for (int rr = 0; rr < 4; ++rr) {
                int row = base + rr;
                if (rr) ws += *(const f32x4*)(X + (row + 18) * 132 + c4)
                            - *(const f32x4*)(X + (row - 1)  * 132 + c4);
                float dv = dtab[row + 27];
                float y4[4] = {ws[0]*dv, ws[1]*dv, ws[2]*dv, ws[3]*dv};
                int off = ywoff(row, c4, 2048);
                pack_split4(y4, Y3h + off, Y3l + off);
            }
        }
        __syncthreads();
    }

    // ---- trailing GEMM3(nc=1) ----
    __builtin_amdgcn_s_setprio(1);
    #pragma unroll
    for (int kt = 0; kt < 4; ++kt) {
        bf16x8 a0[2], a1[2];
        #pragma unroll
        for (int mt = 0; mt < 2; ++mt) {
            int aoff = (wm*2 + mt) * 2048 + kt * 512 + lswz * 8;
            a0[mt] = *(const bf16x8*)(Y3h + aoff);
            a1[mt] = *(const bf16x8*)(Y3l + aoff);
        }
        #pragma unroll
        for (int nt = 0; nt < 2; ++nt) {
            int woff = (nt*4 + wn) * 4096 + (1*4 + kt) * 512 + lane * 8;
            bf16x8 wh = *(const bf16x8*)(wext + W3H + woff);
            bf16x8 wl = *(const bf16x8*)(wext + W3L + woff);
            #pragma unroll
            for (int mt = 0; mt < 2; ++mt) {
                MFMA3(acc3[mt][nt], a0[mt], a1[mt], wh, wl);
            }
        }
    }
    __builtin_amdgcn_s_setprio(0);

    // ---------------- pool: column sums of relu(acc3 + b3) -----------------
    #pragma unroll
    for (int nt = 0; nt < 2; ++nt) {
        int g_t = nt*4 + wn;
        float bv = b3[g_t*16 + l15];
        float cs = 0.f;
        #pragma unroll
        for (int mt = 0; mt < 2; ++mt)
        #pragma unroll
        for (int r = 0; r < 4; ++r) {
            int gr = r0 + (wm*2 + mt)*16 + lg*4 + r;
            if (gr < NN) cs += fmaxf(acc3[mt][nt][r] + bv, 0.f);
        }
        cs += __shfl_xor(cs, 16);
        cs += __shfl_xor(cs, 32);
        if (lane < 16) atomicAdd(&pool[g_t*16 + lane], cs);
    }
    __syncthreads();
    if (tid < 128) partial[((size_t)b * 8 + rt) * 128 + tid] = pool[tid];
}

// ---------------------------------------------------------------------------
// wconv: W fp32 [K][N] -> bf16 hi/lo planes, fragment layout (unswizzled)
// ---------------------------------------------------------------------------
__global__ __launch_bounds__(256) void wconv(
    const float* __restrict__ W1, const float* __restrict__ W2,
    const float* __restrict__ W3, ushort_t* __restrict__ wext)
{
    int i = blockIdx.x * 256 + threadIdx.x;
    float w; int off_h, off_l, idx;
    if (i < 8192) {                       // W1: K=64,  N=128
        int k = i >> 7, n = i & 127;
        w = W1[i]; idx = frag_off(n, k, 1024);  off_h = W1H; off_l = W1L;
    } else if (i < 40960) {               // W2: K=128, N=256
        int j = i - 8192;
        int k = j >> 8, n = j & 255;
        w = W2[j]; idx = frag_off(n, k, 2048);  off_h = W2H; off_l = W2L;
    } else if (i < 73728) {               // W3: K=256, N=128
        int j = i - 40960;
        int k = j >> 7, n = j & 127;
        w = W3[j]; idx = frag_off(n, k, 4096);  off_h = W3H; off_l = W3L;
    } else return;
    __hip_bfloat16 hb = __float2bfloat16(w);
    float hf = __bfloat162float(hb);
    __hip_bfloat16 lb = __float2bfloat16(w - hf);
    wext[off_h + idx] = *(ushort_t*)&hb;
    wext[off_l + idx] = *(ushort_t*)&lb;
}

// ---------------------------------------------------------------------------
// head: gf = mean-pool reduce; features = relu(gf@Wf+bf); out = feats@Wc+bc
// ---------------------------------------------------------------------------
__global__ __launch_bounds__(512) void head_kernel(
    const float* __restrict__ partial, const float* __restrict__ Wf,
    const float* __restrict__ bf, const float* __restrict__ Wc,
    const float* __restrict__ bc, float* __restrict__ dout)
{
    __shared__ float gfs[128];
    __shared__ float feats[512];
    int b = blockIdx.x, t = threadIdx.x;
    if (t < 128) {
        const float* p = partial + (size_t)b * (8 * 128);
        float s = 0.f;
        #pragma unroll
        for (int tt = 0; tt < 8; ++tt) s += p[tt * 128 + t];
        s *= (1.0f / 468.0f);
        gfs[t] = s;
        dout[65792 + b * 128 + t] = s;       // graph_features
    }
    __syncthreads();
    float a = bf[t];
    for (int k = 0; k < 128; ++k) a += gfs[k] * Wf[k * 512 + t];
    a = fmaxf(a, 0.f);
    dout[256 + b * 512 + t] = a;             // features
    feats[t] = a;
    __syncthreads();
    if (t < 64) {
        float s0 = 0.f, s1 = 0.f;
        for (int c = t; c < 512; c += 64) {
            float f = feats[c];
            s0 += f * Wc[c * 2 + 0];
            s1 += f * Wc[c * 2 + 1];
        }
        #pragma unroll
        for (int off = 32; off; off >>= 1) {
            s0 += __shfl_down(s0, off);
            s1 += __shfl_down(s1, off);
        }
        if (t == 0) {
            dout[b * 2 + 0] = s0 + bc[0];
            dout[b * 2 + 1] = s1 + bc[1];
        }
    }
}

// ---------------------------------------------------------------------------
extern "C" void kernel_launch(void* const* d_in, const int* in_sizes, int n_in,
                              void* d_out, int out_size, void* d_ws, size_t ws_size,
                              hipStream_t stream)
{
    const float* landmarks = (const float*)d_in[0];
    const float* W_enc     = (const float*)d_in[1];
    const float* b_enc     = (const float*)d_in[2];
    const float* W1        = (const float*)d_in[3];
    const float* b1        = (const float*)d_in[4];
    const float* W2        = (const float*)d_in[5];
    const float* b2        = (const float*)d_in[6];
    const float* W3        = (const float*)d_in[7];
    const float* b3        = (const float*)d_in[8];
    const float* W_fus     = (const float*)d_in[9];
    const float* b_fus     = (const float*)d_in[10];
    const float* W_cls     = (const float*)d_in[11];
    const float* b_cls     = (const float*)d_in[12];
    float* out = (float*)d_out;

    char* ws = (char*)d_ws;
    ushort_t* wext = (ushort_t*)(ws + 0);        // 294,912 B
    float* partial = (float*)(ws + 294912);      // 524,288 B

    wconv<<<288, 256, 0, stream>>>(W1, W2, W3, wext);
    fused<<<dim3(8, 128), 512, 0, stream>>>(
        landmarks, wext, W_enc, b_enc, b1, b2, b3, partial);
    head_kernel<<<128, 512, 0, stream>>>(partial, W_fus, b_fus, W_cls, b_cls, out);
}